// Round 1
// baseline (4424.772 us; speedup 1.0000x reference)
//
#include <hip/hip_runtime.h>
#include <cstddef>

#define Bb 16
#define Ll 1024
#define OBS 64
#define Hh 256
#define NBLK 4
#define NST 16
#define DCV 4
#define DIN 512
#define DTR 16

// ---------------- workspace layout (floats) ----------------
static const size_t OFF_H0   = 0;
static const size_t OFF_H1   = OFF_H0 + (size_t)Bb * Ll * Hh;        // 4,194,304
static const size_t OFF_XIN  = OFF_H1 + (size_t)Bb * Ll * Hh;        // xin, later reused as dt
static const size_t OFF_Z    = OFF_XIN + (size_t)Bb * Ll * DIN;
static const size_t OFF_U    = OFF_Z   + (size_t)Bb * Ll * DIN;
static const size_t OFF_PROJ = OFF_U   + (size_t)Bb * Ll * DIN;      // [M,48]

// ---------------- generic fp32 GEMM: C[M,N] = A[M,K] * W[N,K]^T ----------------
// ACT: 0 = none, 1 = softplus
// Requires: M % 64 == 0, K % 16 == 0, lda % 4 == 0.
template <int ACT>
__global__ __launch_bounds__(256) void gemm_nt(
    const float* __restrict__ A, int lda,
    const float* __restrict__ W,          // [N, K] row-major
    const float* __restrict__ bias,       // [N] or nullptr
    float* __restrict__ C0,               // cols [0, splitN)
    float* __restrict__ C1,               // cols [splitN, N) (may be nullptr)
    int M, int N, int K, int splitN)
{
    __shared__ float As[16][68];   // +4 pad: conflict-free transposed writes, 16B-aligned rows
    __shared__ float Ws[16][68];

    const int tid = threadIdx.x;
    const int m0 = blockIdx.y * 64;
    const int n0 = blockIdx.x * 64;
    const int tx = tid & 15;       // n sub-tile
    const int ty = tid >> 4;       // m sub-tile

    const int r  = tid >> 2;        // 0..63 : row within tile for staging
    const int kv = (tid & 3) * 4;   // 0,4,8,12 : k-offset for staging

    float acc[4][4] = {};

    for (int k0 = 0; k0 < K; k0 += 16) {
        float4 a4;
        {
            const float* ap = A + (size_t)(m0 + r) * lda + (k0 + kv);
            a4 = *(const float4*)ap;
        }
        float4 w4 = make_float4(0.f, 0.f, 0.f, 0.f);
        if (n0 + r < N) {
            const float* wp = W + (size_t)(n0 + r) * K + (k0 + kv);
            w4 = *(const float4*)wp;
        }
        __syncthreads();  // protect previous iteration's LDS reads
        As[kv + 0][r] = a4.x; As[kv + 1][r] = a4.y;
        As[kv + 2][r] = a4.z; As[kv + 3][r] = a4.w;
        Ws[kv + 0][r] = w4.x; Ws[kv + 1][r] = w4.y;
        Ws[kv + 2][r] = w4.z; Ws[kv + 3][r] = w4.w;
        __syncthreads();
#pragma unroll
        for (int kk = 0; kk < 16; ++kk) {
            float4 av = *(const float4*)&As[kk][ty * 4];
            float4 wv = *(const float4*)&Ws[kk][tx * 4];
            float am[4] = {av.x, av.y, av.z, av.w};
            float wn[4] = {wv.x, wv.y, wv.z, wv.w};
#pragma unroll
            for (int i = 0; i < 4; ++i)
#pragma unroll
                for (int j = 0; j < 4; ++j)
                    acc[i][j] += am[i] * wn[j];
        }
    }

#pragma unroll
    for (int i = 0; i < 4; ++i) {
        const int row = m0 + ty * 4 + i;
#pragma unroll
        for (int j = 0; j < 4; ++j) {
            const int col = n0 + tx * 4 + j;
            if (col >= N) continue;
            float v = acc[i][j];
            if (bias) v += bias[col];
            if (ACT == 1) v = fmaxf(v, 0.f) + log1pf(expf(-fabsf(v)));  // stable softplus
            if (col < splitN)
                C0[(size_t)row * splitN + col] = v;
            else
                C1[(size_t)row * (N - splitN) + (col - splitN)] = v;
        }
    }
}

// ---------------- causal depthwise conv1d + silu ----------------
__global__ __launch_bounds__(256) void conv_silu_kernel(
    const float* __restrict__ xin,   // [B*L, DIN]
    const float* __restrict__ cw,    // [DIN, DC]
    const float* __restrict__ cb,    // [DIN]
    float* __restrict__ u, int total)
{
    int idx = blockIdx.x * 256 + threadIdx.x;
    if (idx >= total) return;
    int d  = idx & (DIN - 1);
    int bl = idx >> 9;
    int l  = bl & (Ll - 1);
    float acc = cb[d];
#pragma unroll
    for (int k = 0; k < DCV; ++k) {
        int ls = l - (DCV - 1) + k;
        if (ls >= 0) acc += xin[idx + (k - (DCV - 1)) * DIN] * cw[d * DCV + k];
    }
    u[idx] = acc / (1.f + expf(-acc));  // silu
}

// ---------------- selective scan + gating (fused), g written in-place over u --------
// thread = (b, d, n); 16 lanes per (b,d) reduce y over n via shfl_xor.
__global__ __launch_bounds__(256) void scan_gate_kernel(
    const float* __restrict__ dt,    // [B*L, DIN]
    const float* __restrict__ u,     // [B*L, DIN]  (also output g)
    const float* __restrict__ proj,  // [B*L, 48]: cols 16..31 = Bc, 32..47 = Cc
    const float* __restrict__ Alog,  // [DIN, NST]
    const float* __restrict__ Dsk,   // [DIN]
    const float* __restrict__ z,     // [B*L, DIN]
    float* __restrict__ g)           // == u
{
    int gid = blockIdx.x * 256 + threadIdx.x;
    int n = gid & 15;
    int d = (gid >> 4) & (DIN - 1);
    int b = gid >> 13;

    const float A  = -expf(Alog[d * NST + n]);
    const float Dv = Dsk[d];
    float h = 0.f;

    const size_t base = (size_t)b * Ll * DIN + d;
    const float* dt_p = dt + base;
    const float* u_p  = u + base;
    const float* z_p  = z + base;
    float* g_p        = g + base;
    const float* pr_p = proj + (size_t)b * Ll * 48;

    for (int l = 0; l < Ll; ++l) {
        float dtv = dt_p[(size_t)l * DIN];
        float uv  = u_p[(size_t)l * DIN];
        float Bn  = pr_p[(size_t)l * 48 + 16 + n];
        float Cn  = pr_p[(size_t)l * 48 + 32 + n];

        h = expf(dtv * A) * h + dtv * uv * Bn;
        float p = h * Cn;
        p += __shfl_xor(p, 1);
        p += __shfl_xor(p, 2);
        p += __shfl_xor(p, 4);
        p += __shfl_xor(p, 8);
        if (n == 0) {
            float zv = z_p[(size_t)l * DIN];
            float sig = zv / (1.f + expf(-zv));
            g_p[(size_t)l * DIN] = (p + Dv * uv) * sig;
        }
    }
}

// ---------------- head: v[b] = h[b, L-1, :] . head_w + head_b ----------------
__global__ void head_kernel(const float* __restrict__ h,
                            const float* __restrict__ hw,
                            const float* __restrict__ hb,
                            float* __restrict__ out)
{
    int b = blockIdx.x;
    int t = threadIdx.x;  // 64
    const float* row = h + ((size_t)b * Ll + (Ll - 1)) * Hh;
    float s = 0.f;
    for (int j = t; j < Hh; j += 64) s += row[j] * hw[j];
#pragma unroll
    for (int off = 32; off; off >>= 1) s += __shfl_down(s, off);
    if (t == 0) out[b] = s + hb[0];
}

extern "C" void kernel_launch(void* const* d_in, const int* in_sizes, int n_in,
                              void* d_out, int out_size, void* d_ws, size_t ws_size,
                              hipStream_t stream)
{
    const float* x    = (const float*)d_in[0];   // [16,1024,64]
    const float* pw   = (const float*)d_in[1];   // [256,64]
    const float* pb   = (const float*)d_in[2];   // [256]
    const float* ipw  = (const float*)d_in[3];   // [4,1024,256]
    const float* cw   = (const float*)d_in[4];   // [4,512,4]
    const float* cb   = (const float*)d_in[5];   // [4,512]
    const float* xpw  = (const float*)d_in[6];   // [4,48,512]
    const float* dpw  = (const float*)d_in[7];   // [4,512,16]
    const float* dpb  = (const float*)d_in[8];   // [4,512]
    const float* Alog = (const float*)d_in[9];   // [4,512,16]
    const float* Dsk  = (const float*)d_in[10];  // [4,512]
    const float* opw  = (const float*)d_in[11];  // [4,256,512]
    const float* hw   = (const float*)d_in[12];  // [1,256]
    const float* hb   = (const float*)d_in[13];  // [1]
    float* out = (float*)d_out;
    float* ws  = (float*)d_ws;

    float* h_buf[2] = { ws + OFF_H0, ws + OFF_H1 };
    float* xin  = ws + OFF_XIN;
    float* zb   = ws + OFF_Z;
    float* ub   = ws + OFF_U;
    float* prj  = ws + OFF_PROJ;
    float* dtb  = xin;  // reuse xin region after conv

    const int M = Bb * Ll;  // 16384

    // h = x @ proj_w^T + proj_b : M x 256, K=64
    gemm_nt<0><<<dim3(Hh / 64, M / 64), 256, 0, stream>>>(
        x, OBS, pw, pb, h_buf[0], nullptr, M, Hh, OBS, Hh);

    int cur = 0;
    for (int i = 0; i < NBLK; ++i) {
        const float* ipw_i = ipw + (size_t)i * 2 * DIN * Hh;
        const float* cw_i  = cw  + (size_t)i * DIN * DCV;
        const float* cb_i  = cb  + (size_t)i * DIN;
        const float* xpw_i = xpw + (size_t)i * 48 * DIN;
        const float* dpw_i = dpw + (size_t)i * DIN * DTR;
        const float* dpb_i = dpb + (size_t)i * DIN;
        const float* Al_i  = Alog + (size_t)i * DIN * NST;
        const float* Dk_i  = Dsk + (size_t)i * DIN;
        const float* opw_i = opw + (size_t)i * Hh * DIN;

        // xz = h @ ipw^T : split into xin / z. N=1024, K=256
        gemm_nt<0><<<dim3(2 * DIN / 64, M / 64), 256, 0, stream>>>(
            h_buf[cur], Hh, ipw_i, nullptr, xin, zb, M, 2 * DIN, Hh, DIN);

        // u = silu(causal depthwise conv(xin) + cb)
        conv_silu_kernel<<<(M * DIN) / 256, 256, 0, stream>>>(
            xin, cw_i, cb_i, ub, M * DIN);

        // proj = u @ xpw^T : N=48, K=512
        gemm_nt<0><<<dim3(1, M / 64), 256, 0, stream>>>(
            ub, DIN, xpw_i, nullptr, prj, nullptr, M, 48, DIN, 48);

        // dt = softplus(dtl @ dpw^T + dpb) : A = proj (first 16 cols, lda=48), N=512, K=16
        gemm_nt<1><<<dim3(DIN / 64, M / 64), 256, 0, stream>>>(
            prj, 48, dpw_i, dpb_i, dtb, nullptr, M, DIN, DTR, DIN);

        // selective scan + gating, writes g in-place over u
        scan_gate_kernel<<<(Bb * DIN * NST) / 256, 256, 0, stream>>>(
            dtb, ub, prj, Al_i, Dk_i, zb, ub);

        // h_next = g @ opw^T : N=256, K=512
        gemm_nt<0><<<dim3(Hh / 64, M / 64), 256, 0, stream>>>(
            ub, DIN, opw_i, nullptr, h_buf[cur ^ 1], nullptr, M, Hh, DIN, Hh);

        cur ^= 1;
    }

    head_kernel<<<Bb, 64, 0, stream>>>(h_buf[cur], hw, hb, out);
}

// Round 2
// 1714.498 us; speedup vs baseline: 2.5808x; 2.5808x over previous
//
#include <hip/hip_runtime.h>
#include <cstddef>

#define Bb 16
#define Ll 1024
#define OBS 64
#define Hh 256
#define NBLK 4
#define NST 16
#define DCV 4
#define DIN 512
#define DTR 16
#define NC 32            // chunks over L
#define CL (Ll / NC)     // 32 steps per chunk

// ---------------- workspace layout (floats) ----------------
static const size_t OFF_H0   = 0;
static const size_t OFF_H1   = OFF_H0 + (size_t)Bb * Ll * Hh;        // 4,194,304
static const size_t OFF_XIN  = OFF_H1 + (size_t)Bb * Ll * Hh;        // xin, later reused as dt
static const size_t OFF_Z    = OFF_XIN + (size_t)Bb * Ll * DIN;
static const size_t OFF_U    = OFF_Z   + (size_t)Bb * Ll * DIN;
static const size_t OFF_PROJ = OFF_U   + (size_t)Bb * Ll * DIN;      // [M,48]
static const size_t OFF_HST  = OFF_PROJ + (size_t)Bb * Ll * 48;      // [B,NC,NST,DIN]
// P overlays h_buf[cur] (dead after in_proj GEMM); F overlays h_buf[cur^1]
// (only written by out_proj GEMM, which runs after the scan kernels).
// Each needs B*NC*NST*DIN = 4,194,304 floats == one h buffer exactly.

// ---------------- generic fp32 GEMM: C[M,N] = A[M,K] * W[N,K]^T ----------------
template <int ACT>
__global__ __launch_bounds__(256) void gemm_nt(
    const float* __restrict__ A, int lda,
    const float* __restrict__ W,          // [N, K] row-major
    const float* __restrict__ bias,       // [N] or nullptr
    float* __restrict__ C0,               // cols [0, splitN)
    float* __restrict__ C1,               // cols [splitN, N) (may be nullptr)
    int M, int N, int K, int splitN)
{
    __shared__ float As[16][68];
    __shared__ float Ws[16][68];

    const int tid = threadIdx.x;
    const int m0 = blockIdx.y * 64;
    const int n0 = blockIdx.x * 64;
    const int tx = tid & 15;
    const int ty = tid >> 4;

    const int r  = tid >> 2;
    const int kv = (tid & 3) * 4;

    float acc[4][4] = {};

    for (int k0 = 0; k0 < K; k0 += 16) {
        float4 a4;
        {
            const float* ap = A + (size_t)(m0 + r) * lda + (k0 + kv);
            a4 = *(const float4*)ap;
        }
        float4 w4 = make_float4(0.f, 0.f, 0.f, 0.f);
        if (n0 + r < N) {
            const float* wp = W + (size_t)(n0 + r) * K + (k0 + kv);
            w4 = *(const float4*)wp;
        }
        __syncthreads();
        As[kv + 0][r] = a4.x; As[kv + 1][r] = a4.y;
        As[kv + 2][r] = a4.z; As[kv + 3][r] = a4.w;
        Ws[kv + 0][r] = w4.x; Ws[kv + 1][r] = w4.y;
        Ws[kv + 2][r] = w4.z; Ws[kv + 3][r] = w4.w;
        __syncthreads();
#pragma unroll
        for (int kk = 0; kk < 16; ++kk) {
            float4 av = *(const float4*)&As[kk][ty * 4];
            float4 wv = *(const float4*)&Ws[kk][tx * 4];
            float am[4] = {av.x, av.y, av.z, av.w};
            float wn[4] = {wv.x, wv.y, wv.z, wv.w};
#pragma unroll
            for (int i = 0; i < 4; ++i)
#pragma unroll
                for (int j = 0; j < 4; ++j)
                    acc[i][j] += am[i] * wn[j];
        }
    }

#pragma unroll
    for (int i = 0; i < 4; ++i) {
        const int row = m0 + ty * 4 + i;
#pragma unroll
        for (int j = 0; j < 4; ++j) {
            const int col = n0 + tx * 4 + j;
            if (col >= N) continue;
            float v = acc[i][j];
            if (bias) v += bias[col];
            if (ACT == 1) v = fmaxf(v, 0.f) + log1pf(expf(-fabsf(v)));
            if (col < splitN)
                C0[(size_t)row * splitN + col] = v;
            else
                C1[(size_t)row * (N - splitN) + (col - splitN)] = v;
        }
    }
}

// ---------------- causal depthwise conv1d + silu ----------------
__global__ __launch_bounds__(256) void conv_silu_kernel(
    const float* __restrict__ xin,
    const float* __restrict__ cw,
    const float* __restrict__ cb,
    float* __restrict__ u, int total)
{
    int idx = blockIdx.x * 256 + threadIdx.x;
    if (idx >= total) return;
    int d  = idx & (DIN - 1);
    int bl = idx >> 9;
    int l  = bl & (Ll - 1);
    float acc = cb[d];
#pragma unroll
    for (int k = 0; k < DCV; ++k) {
        int ls = l - (DCV - 1) + k;
        if (ls >= 0) acc += xin[idx + (k - (DCV - 1)) * DIN] * cw[d * DCV + k];
    }
    u[idx] = acc / (1.f + expf(-acc));
}

// ---------------- scan phase A: chunk-local reduce ----------------
// thread = (b, c, d), d is lane-fast. All 16 n-states in registers.
// P[b,c,n,d] = prod of e over chunk;  F[b,c,n,d] = h at chunk end from h=0.
__global__ __launch_bounds__(256) void scan_chunk_reduce(
    const float* __restrict__ dt,    // [B*L, DIN]
    const float* __restrict__ u,     // [B*L, DIN]
    const float* __restrict__ proj,  // [B*L, 48]
    const float* __restrict__ Alog,  // [DIN, NST]
    float* __restrict__ P,           // [B, NC, NST, DIN]
    float* __restrict__ F)
{
    int gid = blockIdx.x * 256 + threadIdx.x;
    int d = gid & (DIN - 1);
    int c = (gid >> 9) & (NC - 1);
    int b = gid >> 14;

    float A[NST];
#pragma unroll
    for (int n = 0; n < NST; ++n) A[n] = -__expf(Alog[d * NST + n]);

    float h[NST], p[NST];
#pragma unroll
    for (int n = 0; n < NST; ++n) { h[n] = 0.f; p[n] = 1.f; }

    const int l0 = c * CL;
    for (int l = l0; l < l0 + CL; ++l) {
        size_t row = (size_t)b * Ll + l;
        float dtv = dt[row * DIN + d];
        float uv  = u[row * DIN + d];
        float du  = dtv * uv;
        const float* pr = proj + row * 48 + DTR;   // Bc at cols 16..31
        float4 B0 = *(const float4*)(pr + 0);
        float4 B1 = *(const float4*)(pr + 4);
        float4 B2 = *(const float4*)(pr + 8);
        float4 B3 = *(const float4*)(pr + 12);
        float Bn[NST] = {B0.x, B0.y, B0.z, B0.w, B1.x, B1.y, B1.z, B1.w,
                         B2.x, B2.y, B2.z, B2.w, B3.x, B3.y, B3.z, B3.w};
#pragma unroll
        for (int n = 0; n < NST; ++n) {
            float e = __expf(dtv * A[n]);
            h[n] = e * h[n] + du * Bn[n];
            p[n] *= e;
        }
    }

    size_t base = (((size_t)b * NC + c) * NST) * DIN + d;
#pragma unroll
    for (int n = 0; n < NST; ++n) {
        P[base + (size_t)n * DIN] = p[n];
        F[base + (size_t)n * DIN] = h[n];
    }
}

// ---------------- scan phase B: prefix over chunks ----------------
// thread = (b, n, d), d lane-fast. Writes h_start per chunk.
__global__ __launch_bounds__(256) void scan_prefix(
    const float* __restrict__ P,
    const float* __restrict__ F,
    float* __restrict__ HST)         // [B, NC, NST, DIN]
{
    int gid = blockIdx.x * 256 + threadIdx.x;
    int d = gid & (DIN - 1);
    int n = (gid >> 9) & (NST - 1);
    int b = gid >> 13;

    float h = 0.f;
    for (int c = 0; c < NC; ++c) {
        size_t idx = (((size_t)b * NC + c) * NST + n) * DIN + d;
        HST[idx] = h;
        h = P[idx] * h + F[idx];
    }
}

// ---------------- scan phase C: rescan from true h_start + gate ----------------
// thread = (b, c, d). y computed in-register over 16 n; g written over u.
__global__ __launch_bounds__(256) void scan_rescan_gate(
    const float* __restrict__ dt,
    const float* __restrict__ u,     // also output g
    const float* __restrict__ proj,
    const float* __restrict__ Alog,
    const float* __restrict__ Dsk,
    const float* __restrict__ z,
    const float* __restrict__ HST,
    float* __restrict__ g)
{
    int gid = blockIdx.x * 256 + threadIdx.x;
    int d = gid & (DIN - 1);
    int c = (gid >> 9) & (NC - 1);
    int b = gid >> 14;

    float A[NST];
#pragma unroll
    for (int n = 0; n < NST; ++n) A[n] = -__expf(Alog[d * NST + n]);
    const float Dv = Dsk[d];

    float h[NST];
    {
        size_t base = (((size_t)b * NC + c) * NST) * DIN + d;
#pragma unroll
        for (int n = 0; n < NST; ++n) h[n] = HST[base + (size_t)n * DIN];
    }

    const int l0 = c * CL;
    for (int l = l0; l < l0 + CL; ++l) {
        size_t row = (size_t)b * Ll + l;
        float dtv = dt[row * DIN + d];
        float uv  = u[row * DIN + d];
        float du  = dtv * uv;
        const float* pr = proj + row * 48 + DTR;
        float4 B0 = *(const float4*)(pr + 0);
        float4 B1 = *(const float4*)(pr + 4);
        float4 B2 = *(const float4*)(pr + 8);
        float4 B3 = *(const float4*)(pr + 12);
        float4 C0 = *(const float4*)(pr + 16);
        float4 C1 = *(const float4*)(pr + 20);
        float4 C2 = *(const float4*)(pr + 24);
        float4 C3 = *(const float4*)(pr + 28);
        float Bn[NST] = {B0.x, B0.y, B0.z, B0.w, B1.x, B1.y, B1.z, B1.w,
                         B2.x, B2.y, B2.z, B2.w, B3.x, B3.y, B3.z, B3.w};
        float Cn[NST] = {C0.x, C0.y, C0.z, C0.w, C1.x, C1.y, C1.z, C1.w,
                         C2.x, C2.y, C2.z, C2.w, C3.x, C3.y, C3.z, C3.w};
        float y = 0.f;
#pragma unroll
        for (int n = 0; n < NST; ++n) {
            float e = __expf(dtv * A[n]);
            h[n] = e * h[n] + du * Bn[n];
            y += h[n] * Cn[n];
        }
        float zv = z[row * DIN + d];
        float sig = zv / (1.f + __expf(-zv));
        g[row * DIN + d] = (y + Dv * uv) * sig;
    }
}

// ---------------- head ----------------
__global__ void head_kernel(const float* __restrict__ h,
                            const float* __restrict__ hw,
                            const float* __restrict__ hb,
                            float* __restrict__ out)
{
    int b = blockIdx.x;
    int t = threadIdx.x;  // 64
    const float* row = h + ((size_t)b * Ll + (Ll - 1)) * Hh;
    float s = 0.f;
    for (int j = t; j < Hh; j += 64) s += row[j] * hw[j];
#pragma unroll
    for (int off = 32; off; off >>= 1) s += __shfl_down(s, off);
    if (t == 0) out[b] = s + hb[0];
}

extern "C" void kernel_launch(void* const* d_in, const int* in_sizes, int n_in,
                              void* d_out, int out_size, void* d_ws, size_t ws_size,
                              hipStream_t stream)
{
    const float* x    = (const float*)d_in[0];
    const float* pw   = (const float*)d_in[1];
    const float* pb   = (const float*)d_in[2];
    const float* ipw  = (const float*)d_in[3];
    const float* cw   = (const float*)d_in[4];
    const float* cb   = (const float*)d_in[5];
    const float* xpw  = (const float*)d_in[6];
    const float* dpw  = (const float*)d_in[7];
    const float* dpb  = (const float*)d_in[8];
    const float* Alog = (const float*)d_in[9];
    const float* Dsk  = (const float*)d_in[10];
    const float* opw  = (const float*)d_in[11];
    const float* hw   = (const float*)d_in[12];
    const float* hb   = (const float*)d_in[13];
    float* out = (float*)d_out;
    float* ws  = (float*)d_ws;

    float* h_buf[2] = { ws + OFF_H0, ws + OFF_H1 };
    float* xin  = ws + OFF_XIN;
    float* zb   = ws + OFF_Z;
    float* ub   = ws + OFF_U;
    float* prj  = ws + OFF_PROJ;
    float* hst  = ws + OFF_HST;
    float* dtb  = xin;  // reuse xin region after conv

    const int M = Bb * Ll;  // 16384

    gemm_nt<0><<<dim3(Hh / 64, M / 64), 256, 0, stream>>>(
        x, OBS, pw, pb, h_buf[0], nullptr, M, Hh, OBS, Hh);

    int cur = 0;
    for (int i = 0; i < NBLK; ++i) {
        const float* ipw_i = ipw + (size_t)i * 2 * DIN * Hh;
        const float* cw_i  = cw  + (size_t)i * DIN * DCV;
        const float* cb_i  = cb  + (size_t)i * DIN;
        const float* xpw_i = xpw + (size_t)i * 48 * DIN;
        const float* dpw_i = dpw + (size_t)i * DIN * DTR;
        const float* dpb_i = dpb + (size_t)i * DIN;
        const float* Al_i  = Alog + (size_t)i * DIN * NST;
        const float* Dk_i  = Dsk + (size_t)i * DIN;
        const float* opw_i = opw + (size_t)i * Hh * DIN;

        // xz = h @ ipw^T : split into xin / z
        gemm_nt<0><<<dim3(2 * DIN / 64, M / 64), 256, 0, stream>>>(
            h_buf[cur], Hh, ipw_i, nullptr, xin, zb, M, 2 * DIN, Hh, DIN);

        // u = silu(conv(xin) + cb)
        conv_silu_kernel<<<(M * DIN) / 256, 256, 0, stream>>>(
            xin, cw_i, cb_i, ub, M * DIN);

        // proj = u @ xpw^T
        gemm_nt<0><<<dim3(1, M / 64), 256, 0, stream>>>(
            ub, DIN, xpw_i, nullptr, prj, nullptr, M, 48, DIN, 48);

        // dt = softplus(dtl @ dpw^T + dpb)   (overwrites xin)
        gemm_nt<1><<<dim3(DIN / 64, M / 64), 256, 0, stream>>>(
            prj, 48, dpw_i, dpb_i, dtb, nullptr, M, DIN, DTR, DIN);

        // ---- chunked scan ----
        float* Pbuf = h_buf[cur];      // dead after in_proj GEMM
        float* Fbuf = h_buf[cur ^ 1];  // overwritten later by out_proj GEMM
        scan_chunk_reduce<<<(Bb * NC * DIN) / 256, 256, 0, stream>>>(
            dtb, ub, prj, Al_i, Pbuf, Fbuf);
        scan_prefix<<<(Bb * NST * DIN) / 256, 256, 0, stream>>>(
            Pbuf, Fbuf, hst);
        scan_rescan_gate<<<(Bb * NC * DIN) / 256, 256, 0, stream>>>(
            dtb, ub, prj, Al_i, Dk_i, zb, hst, ub);

        // h_next = g @ opw^T
        gemm_nt<0><<<dim3(Hh / 64, M / 64), 256, 0, stream>>>(
            ub, DIN, opw_i, nullptr, h_buf[cur ^ 1], nullptr, M, Hh, DIN, Hh);

        cur ^= 1;
    }

    head_kernel<<<Bb, 64, 0, stream>>>(h_buf[cur], hw, hb, out);
}

// Round 3
// 1198.464 us; speedup vs baseline: 3.6920x; 1.4306x over previous
//
#include <hip/hip_runtime.h>
#include <cstddef>

#define Bb 16
#define Ll 1024
#define OBS 64
#define Hh 256
#define NBLK 4
#define NST 16
#define DCV 4
#define DIN 512
#define DTR 16
#define NC 32            // chunks over L
#define CL (Ll / NC)     // 32 steps per chunk

typedef short short8 __attribute__((ext_vector_type(8)));
typedef float f32x4 __attribute__((ext_vector_type(4)));

// ---------------- workspace layout (floats) ----------------
static const size_t OFF_H0   = 0;
static const size_t OFF_H1   = OFF_H0 + (size_t)Bb * Ll * Hh;        // 4,194,304
static const size_t OFF_XIN  = OFF_H1 + (size_t)Bb * Ll * Hh;        // xin, later reused as dt
static const size_t OFF_Z    = OFF_XIN + (size_t)Bb * Ll * DIN;
static const size_t OFF_U    = OFF_Z   + (size_t)Bb * Ll * DIN;
static const size_t OFF_PROJ = OFF_U   + (size_t)Bb * Ll * DIN;      // [M,48]
static const size_t OFF_HST  = OFF_PROJ + (size_t)Bb * Ll * 48;      // [B,NC,NST,DIN]
static const size_t OFF_WC   = OFF_HST + (size_t)Bb * NC * NST * DIN; // bf16 hi/lo weights
// ushort offsets inside WC region:
static const size_t WPW_HI  = 0;                   // 16384
static const size_t WPW_LO  = 16384;
static const size_t WIPW_HI = 32768;               // 1,048,576
static const size_t WIPW_LO = WIPW_HI + 1048576;
static const size_t WOPW_HI = WIPW_LO + 1048576;   // 524,288
static const size_t WOPW_LO = WOPW_HI + 524288;

__device__ inline unsigned short f32_to_bf16(float v) {
    unsigned int u = __float_as_uint(v);
    u += 0x7fffu + ((u >> 16) & 1u);
    return (unsigned short)(u >> 16);
}
__device__ inline float bf16_to_f32(unsigned short h) {
    return __uint_as_float((unsigned int)h << 16);
}

// ---------------- weight fp32 -> bf16 hi/lo conversion ----------------
__global__ __launch_bounds__(256) void convert_w_kernel(
    const float* __restrict__ w,
    unsigned short* __restrict__ hi,
    unsigned short* __restrict__ lo, int n4)
{
    int i = blockIdx.x * 256 + threadIdx.x;
    if (i >= n4) return;
    float4 v4 = ((const float4*)w)[i];
    float vv[4] = {v4.x, v4.y, v4.z, v4.w};
#pragma unroll
    for (int e = 0; e < 4; ++e) {
        unsigned short hb = f32_to_bf16(vv[e]);
        float res = vv[e] - bf16_to_f32(hb);
        hi[i * 4 + e] = hb;
        lo[i * 4 + e] = f32_to_bf16(res);
    }
}

// ---------------- bf16x3 MFMA GEMM: C[M,N'] = A[M,K](fp32) * W[N,K]^T ----------------
// W pre-split into bf16 hi/lo. A converted in-register while staging.
// BM x 128 tile, BK=32, 4 waves. Requires N % 128 == 0, K % 32 == 0.
template <int BM, int WR>
__global__ __launch_bounds__(256) void gemm_mfma3(
    const float* __restrict__ A, int lda,
    const unsigned short* __restrict__ Whi,
    const unsigned short* __restrict__ Wlo,
    const float* __restrict__ bias,
    float* __restrict__ C0,              // cols [0, splitN)
    float* __restrict__ C1,              // cols [splitN, N)
    int N, int K, int splitN)
{
    constexpr int WC_ = 4 / WR;             // wave cols
    constexpr int MI = (BM / WR) / 16;      // m fragments per wave
    constexpr int NJ = (128 / WC_) / 16;    // n fragments per wave
    constexpr int ASLOT = BM * 4 / 256;     // (row,kb) slots per thread for A

    __shared__ unsigned short AsH[BM * 32], AsL[BM * 32];
    __shared__ unsigned short BsH[128 * 32], BsL[128 * 32];

    const int tid  = threadIdx.x;
    const int lane = tid & 63;
    const int w    = tid >> 6;
    const int wr   = w / WC_;
    const int wc   = w % WC_;
    const int m0   = blockIdx.y * BM;
    const int n0   = blockIdx.x * 128;

    f32x4 acc[MI][NJ] = {};

    for (int k0 = 0; k0 < K; k0 += 32) {
        // ---- stage A: fp32 -> bf16 hi/lo in-register ----
#pragma unroll
        for (int sI = 0; sI < ASLOT; ++sI) {
            int s = tid + sI * 256;
            int row = s >> 2, kb = s & 3;
            const float* ap = A + (size_t)(m0 + row) * lda + k0 + kb * 8;
            float4 v0 = *(const float4*)ap;
            float4 v1 = *(const float4*)(ap + 4);
            float vv[8] = {v0.x, v0.y, v0.z, v0.w, v1.x, v1.y, v1.z, v1.w};
            short8 h8, l8;
#pragma unroll
            for (int e = 0; e < 8; ++e) {
                unsigned short hb = f32_to_bf16(vv[e]);
                float res = vv[e] - bf16_to_f32(hb);
                h8[e] = (short)hb;
                l8[e] = (short)f32_to_bf16(res);
            }
            *(short8*)&AsH[s * 8] = h8;
            *(short8*)&AsL[s * 8] = l8;
        }
        // ---- stage B: pre-converted bf16 hi/lo ----
#pragma unroll
        for (int sI = 0; sI < 2; ++sI) {
            int s = tid + sI * 256;
            int row = s >> 2, kb = s & 3;
            size_t off = (size_t)(n0 + row) * K + k0 + kb * 8;
            *(short8*)&BsH[s * 8] = *(const short8*)(Whi + off);
            *(short8*)&BsL[s * 8] = *(const short8*)(Wlo + off);
        }
        __syncthreads();

        // ---- fragments + 3-pass MFMA ----
        const int rr = lane & 15;
        const int kq = lane >> 4;
        short8 ah[MI], al[MI];
#pragma unroll
        for (int i = 0; i < MI; ++i) {
            int row = wr * (BM / WR) + i * 16 + rr;
            ah[i] = *(const short8*)&AsH[row * 32 + kq * 8];
            al[i] = *(const short8*)&AsL[row * 32 + kq * 8];
        }
#pragma unroll
        for (int j = 0; j < NJ; ++j) {
            int col = wc * (128 / WC_) + j * 16 + rr;
            short8 bh = *(const short8*)&BsH[col * 32 + kq * 8];
            short8 bl = *(const short8*)&BsL[col * 32 + kq * 8];
#pragma unroll
            for (int i = 0; i < MI; ++i) {
                acc[i][j] = __builtin_amdgcn_mfma_f32_16x16x32_bf16(ah[i], bh, acc[i][j], 0, 0, 0);
                acc[i][j] = __builtin_amdgcn_mfma_f32_16x16x32_bf16(ah[i], bl, acc[i][j], 0, 0, 0);
                acc[i][j] = __builtin_amdgcn_mfma_f32_16x16x32_bf16(al[i], bh, acc[i][j], 0, 0, 0);
            }
        }
        __syncthreads();
    }

    // ---- epilogue: C/D layout col=lane&15, row=(lane>>4)*4+r ----
    const int rr = lane & 15;
    const int rq = lane >> 4;
#pragma unroll
    for (int i = 0; i < MI; ++i) {
#pragma unroll
        for (int j = 0; j < NJ; ++j) {
            int col = n0 + wc * (128 / WC_) + j * 16 + rr;
            float badd = bias ? bias[col] : 0.f;
#pragma unroll
            for (int r = 0; r < 4; ++r) {
                int row = m0 + wr * (BM / WR) + i * 16 + rq * 4 + r;
                float v = acc[i][j][r] + badd;
                if (col < splitN)
                    C0[(size_t)row * splitN + col] = v;
                else
                    C1[(size_t)row * (N - splitN) + (col - splitN)] = v;
            }
        }
    }
}

// ---------------- fp32 GEMM (kept for small/odd shapes): C = A * W^T ----------------
template <int ACT>
__global__ __launch_bounds__(256) void gemm_nt(
    const float* __restrict__ A, int lda,
    const float* __restrict__ W,
    const float* __restrict__ bias,
    float* __restrict__ C0, float* __restrict__ C1,
    int M, int N, int K, int splitN)
{
    __shared__ float As[16][68];
    __shared__ float Ws[16][68];

    const int tid = threadIdx.x;
    const int m0 = blockIdx.y * 64;
    const int n0 = blockIdx.x * 64;
    const int tx = tid & 15;
    const int ty = tid >> 4;
    const int r  = tid >> 2;
    const int kv = (tid & 3) * 4;

    float acc[4][4] = {};

    for (int k0 = 0; k0 < K; k0 += 16) {
        float4 a4;
        {
            const float* ap = A + (size_t)(m0 + r) * lda + (k0 + kv);
            a4 = *(const float4*)ap;
        }
        float4 w4 = make_float4(0.f, 0.f, 0.f, 0.f);
        if (n0 + r < N) {
            const float* wp = W + (size_t)(n0 + r) * K + (k0 + kv);
            w4 = *(const float4*)wp;
        }
        __syncthreads();
        As[kv + 0][r] = a4.x; As[kv + 1][r] = a4.y;
        As[kv + 2][r] = a4.z; As[kv + 3][r] = a4.w;
        Ws[kv + 0][r] = w4.x; Ws[kv + 1][r] = w4.y;
        Ws[kv + 2][r] = w4.z; Ws[kv + 3][r] = w4.w;
        __syncthreads();
#pragma unroll
        for (int kk = 0; kk < 16; ++kk) {
            float4 av = *(const float4*)&As[kk][ty * 4];
            float4 wv = *(const float4*)&Ws[kk][tx * 4];
            float am[4] = {av.x, av.y, av.z, av.w};
            float wn[4] = {wv.x, wv.y, wv.z, wv.w};
#pragma unroll
            for (int i = 0; i < 4; ++i)
#pragma unroll
                for (int j = 0; j < 4; ++j)
                    acc[i][j] += am[i] * wn[j];
        }
    }

#pragma unroll
    for (int i = 0; i < 4; ++i) {
        const int row = m0 + ty * 4 + i;
#pragma unroll
        for (int j = 0; j < 4; ++j) {
            const int col = n0 + tx * 4 + j;
            if (col >= N) continue;
            float v = acc[i][j];
            if (bias) v += bias[col];
            if (ACT == 1) v = fmaxf(v, 0.f) + log1pf(expf(-fabsf(v)));
            if (col < splitN)
                C0[(size_t)row * splitN + col] = v;
            else
                C1[(size_t)row * (N - splitN) + (col - splitN)] = v;
        }
    }
}

// ---------------- causal depthwise conv1d + silu ----------------
__global__ __launch_bounds__(256) void conv_silu_kernel(
    const float* __restrict__ xin,
    const float* __restrict__ cw,
    const float* __restrict__ cb,
    float* __restrict__ u, int total)
{
    int idx = blockIdx.x * 256 + threadIdx.x;
    if (idx >= total) return;
    int d  = idx & (DIN - 1);
    int bl = idx >> 9;
    int l  = bl & (Ll - 1);
    float acc = cb[d];
#pragma unroll
    for (int k = 0; k < DCV; ++k) {
        int ls = l - (DCV - 1) + k;
        if (ls >= 0) acc += xin[idx + (k - (DCV - 1)) * DIN] * cw[d * DCV + k];
    }
    u[idx] = acc / (1.f + expf(-acc));
}

// ---------------- scan phase A: chunk-local reduce ----------------
__global__ __launch_bounds__(256) void scan_chunk_reduce(
    const float* __restrict__ dt,
    const float* __restrict__ u,
    const float* __restrict__ proj,
    const float* __restrict__ Alog,
    float* __restrict__ P,
    float* __restrict__ F)
{
    int gid = blockIdx.x * 256 + threadIdx.x;
    int d = gid & (DIN - 1);
    int c = (gid >> 9) & (NC - 1);
    int b = gid >> 14;

    float A[NST];
#pragma unroll
    for (int n = 0; n < NST; ++n) A[n] = -__expf(Alog[d * NST + n]);

    float h[NST], p[NST];
#pragma unroll
    for (int n = 0; n < NST; ++n) { h[n] = 0.f; p[n] = 1.f; }

    const int l0 = c * CL;
    for (int l = l0; l < l0 + CL; ++l) {
        size_t row = (size_t)b * Ll + l;
        float dtv = dt[row * DIN + d];
        float uv  = u[row * DIN + d];
        float du  = dtv * uv;
        const float* pr = proj + row * 48 + DTR;
        float4 B0 = *(const float4*)(pr + 0);
        float4 B1 = *(const float4*)(pr + 4);
        float4 B2 = *(const float4*)(pr + 8);
        float4 B3 = *(const float4*)(pr + 12);
        float Bn[NST] = {B0.x, B0.y, B0.z, B0.w, B1.x, B1.y, B1.z, B1.w,
                         B2.x, B2.y, B2.z, B2.w, B3.x, B3.y, B3.z, B3.w};
#pragma unroll
        for (int n = 0; n < NST; ++n) {
            float e = __expf(dtv * A[n]);
            h[n] = e * h[n] + du * Bn[n];
            p[n] *= e;
        }
    }

    size_t base = (((size_t)b * NC + c) * NST) * DIN + d;
#pragma unroll
    for (int n = 0; n < NST; ++n) {
        P[base + (size_t)n * DIN] = p[n];
        F[base + (size_t)n * DIN] = h[n];
    }
}

// ---------------- scan phase B: prefix over chunks ----------------
__global__ __launch_bounds__(256) void scan_prefix(
    const float* __restrict__ P,
    const float* __restrict__ F,
    float* __restrict__ HST)
{
    int gid = blockIdx.x * 256 + threadIdx.x;
    int d = gid & (DIN - 1);
    int n = (gid >> 9) & (NST - 1);
    int b = gid >> 13;

    float h = 0.f;
    for (int c = 0; c < NC; ++c) {
        size_t idx = (((size_t)b * NC + c) * NST + n) * DIN + d;
        HST[idx] = h;
        h = P[idx] * h + F[idx];
    }
}

// ---------------- scan phase C: rescan + gate ----------------
__global__ __launch_bounds__(256) void scan_rescan_gate(
    const float* __restrict__ dt,
    const float* __restrict__ u,
    const float* __restrict__ proj,
    const float* __restrict__ Alog,
    const float* __restrict__ Dsk,
    const float* __restrict__ z,
    const float* __restrict__ HST,
    float* __restrict__ g)
{
    int gid = blockIdx.x * 256 + threadIdx.x;
    int d = gid & (DIN - 1);
    int c = (gid >> 9) & (NC - 1);
    int b = gid >> 14;

    float A[NST];
#pragma unroll
    for (int n = 0; n < NST; ++n) A[n] = -__expf(Alog[d * NST + n]);
    const float Dv = Dsk[d];

    float h[NST];
    {
        size_t base = (((size_t)b * NC + c) * NST) * DIN + d;
#pragma unroll
        for (int n = 0; n < NST; ++n) h[n] = HST[base + (size_t)n * DIN];
    }

    const int l0 = c * CL;
    for (int l = l0; l < l0 + CL; ++l) {
        size_t row = (size_t)b * Ll + l;
        float dtv = dt[row * DIN + d];
        float uv  = u[row * DIN + d];
        float du  = dtv * uv;
        const float* pr = proj + row * 48 + DTR;
        float4 B0 = *(const float4*)(pr + 0);
        float4 B1 = *(const float4*)(pr + 4);
        float4 B2 = *(const float4*)(pr + 8);
        float4 B3 = *(const float4*)(pr + 12);
        float4 C0 = *(const float4*)(pr + 16);
        float4 C1 = *(const float4*)(pr + 20);
        float4 C2 = *(const float4*)(pr + 24);
        float4 C3 = *(const float4*)(pr + 28);
        float Bn[NST] = {B0.x, B0.y, B0.z, B0.w, B1.x, B1.y, B1.z, B1.w,
                         B2.x, B2.y, B2.z, B2.w, B3.x, B3.y, B3.z, B3.w};
        float Cn[NST] = {C0.x, C0.y, C0.z, C0.w, C1.x, C1.y, C1.z, C1.w,
                         C2.x, C2.y, C2.z, C2.w, C3.x, C3.y, C3.z, C3.w};
        float y = 0.f;
#pragma unroll
        for (int n = 0; n < NST; ++n) {
            float e = __expf(dtv * A[n]);
            h[n] = e * h[n] + du * Bn[n];
            y += h[n] * Cn[n];
        }
        float zv = z[row * DIN + d];
        float sig = zv / (1.f + __expf(-zv));
        g[row * DIN + d] = (y + Dv * uv) * sig;
    }
}

// ---------------- head ----------------
__global__ void head_kernel(const float* __restrict__ h,
                            const float* __restrict__ hw,
                            const float* __restrict__ hb,
                            float* __restrict__ out)
{
    int b = blockIdx.x;
    int t = threadIdx.x;  // 64
    const float* row = h + ((size_t)b * Ll + (Ll - 1)) * Hh;
    float s = 0.f;
    for (int j = t; j < Hh; j += 64) s += row[j] * hw[j];
#pragma unroll
    for (int off = 32; off; off >>= 1) s += __shfl_down(s, off);
    if (t == 0) out[b] = s + hb[0];
}

extern "C" void kernel_launch(void* const* d_in, const int* in_sizes, int n_in,
                              void* d_out, int out_size, void* d_ws, size_t ws_size,
                              hipStream_t stream)
{
    const float* x    = (const float*)d_in[0];
    const float* pw   = (const float*)d_in[1];
    const float* pb   = (const float*)d_in[2];
    const float* ipw  = (const float*)d_in[3];
    const float* cw   = (const float*)d_in[4];
    const float* cb   = (const float*)d_in[5];
    const float* xpw  = (const float*)d_in[6];
    const float* dpw  = (const float*)d_in[7];
    const float* dpb  = (const float*)d_in[8];
    const float* Alog = (const float*)d_in[9];
    const float* Dsk  = (const float*)d_in[10];
    const float* opw  = (const float*)d_in[11];
    const float* hw   = (const float*)d_in[12];
    const float* hb   = (const float*)d_in[13];
    float* out = (float*)d_out;
    float* ws  = (float*)d_ws;

    float* h_buf[2] = { ws + OFF_H0, ws + OFF_H1 };
    float* xin  = ws + OFF_XIN;
    float* zb   = ws + OFF_Z;
    float* ub   = ws + OFF_U;
    float* prj  = ws + OFF_PROJ;
    float* hst  = ws + OFF_HST;
    float* dtb  = xin;
    unsigned short* wc = (unsigned short*)(ws + OFF_WC);

    const int M = Bb * Ll;  // 16384

    // ---- pre-convert weights to bf16 hi/lo ----
    convert_w_kernel<<<(Hh * OBS / 4 + 255) / 256, 256, 0, stream>>>(
        pw, wc + WPW_HI, wc + WPW_LO, Hh * OBS / 4);
    convert_w_kernel<<<(NBLK * 2 * DIN * Hh / 4 + 255) / 256, 256, 0, stream>>>(
        ipw, wc + WIPW_HI, wc + WIPW_LO, NBLK * 2 * DIN * Hh / 4);
    convert_w_kernel<<<(NBLK * Hh * DIN / 4 + 255) / 256, 256, 0, stream>>>(
        opw, wc + WOPW_HI, wc + WOPW_LO, NBLK * Hh * DIN / 4);

    // h = x @ proj_w^T + proj_b : M x 256, K=64 (MFMA)
    gemm_mfma3<64, 1><<<dim3(Hh / 128, M / 64), 256, 0, stream>>>(
        x, OBS, wc + WPW_HI, wc + WPW_LO, pb, h_buf[0], nullptr, Hh, OBS, Hh);

    int cur = 0;
    for (int i = 0; i < NBLK; ++i) {
        const unsigned short* ipwh = wc + WIPW_HI + (size_t)i * 2 * DIN * Hh;
        const unsigned short* ipwl = wc + WIPW_LO + (size_t)i * 2 * DIN * Hh;
        const unsigned short* opwh = wc + WOPW_HI + (size_t)i * Hh * DIN;
        const unsigned short* opwl = wc + WOPW_LO + (size_t)i * Hh * DIN;
        const float* cw_i  = cw  + (size_t)i * DIN * DCV;
        const float* cb_i  = cb  + (size_t)i * DIN;
        const float* xpw_i = xpw + (size_t)i * 48 * DIN;
        const float* dpw_i = dpw + (size_t)i * DIN * DTR;
        const float* dpb_i = dpb + (size_t)i * DIN;
        const float* Al_i  = Alog + (size_t)i * DIN * NST;
        const float* Dk_i  = Dsk + (size_t)i * DIN;

        // xz = h @ ipw^T -> split xin / z : N=1024, K=256 (MFMA)
        gemm_mfma3<128, 2><<<dim3(2 * DIN / 128, M / 128), 256, 0, stream>>>(
            h_buf[cur], Hh, ipwh, ipwl, nullptr, xin, zb, 2 * DIN, Hh, DIN);

        // u = silu(conv(xin) + cb)
        conv_silu_kernel<<<(M * DIN) / 256, 256, 0, stream>>>(
            xin, cw_i, cb_i, ub, M * DIN);

        // proj = u @ xpw^T : N=48 (fp32)
        gemm_nt<0><<<dim3(1, M / 64), 256, 0, stream>>>(
            ub, DIN, xpw_i, nullptr, prj, nullptr, M, 48, DIN, 48);

        // dt = softplus(dtl @ dpw^T + dpb) : K=16 (fp32), overwrites xin
        gemm_nt<1><<<dim3(DIN / 64, M / 64), 256, 0, stream>>>(
            prj, 48, dpw_i, dpb_i, dtb, nullptr, M, DIN, DTR, DIN);

        // ---- chunked scan ----
        float* Pbuf = h_buf[cur];
        float* Fbuf = h_buf[cur ^ 1];
        scan_chunk_reduce<<<(Bb * NC * DIN) / 256, 256, 0, stream>>>(
            dtb, ub, prj, Al_i, Pbuf, Fbuf);
        scan_prefix<<<(Bb * NST * DIN) / 256, 256, 0, stream>>>(
            Pbuf, Fbuf, hst);
        scan_rescan_gate<<<(Bb * NC * DIN) / 256, 256, 0, stream>>>(
            dtb, ub, prj, Al_i, Dk_i, zb, hst, ub);

        // h_next = g @ opw^T : N=256, K=512 (MFMA)
        gemm_mfma3<64, 1><<<dim3(Hh / 128, M / 64), 256, 0, stream>>>(
            ub, DIN, opwh, opwl, nullptr, h_buf[cur ^ 1], nullptr, Hh, DIN, Hh);

        cur ^= 1;
    }

    head_kernel<<<Bb, 64, 0, stream>>>(h_buf[cur], hw, hb, out);
}